// Round 14
// baseline (120.699 us; speedup 1.0000x reference)
//
#include <hip/hip_runtime.h>

// B=4, S=4096, D=64, fp32. Softmax over QUERY axis (per key-column norm):
//   out[b,q,:] = sum_k exp(s[q,k]) * (1/sum_q' exp(s[q',k])) * V[k,:],  s = Q.K^T/8
// v15: BYTES-BOUND FIX (v14 closed: 9375cy/iter = 192KB/iter / ~20B/cy/CU).
// 4-way chunk reuse: block = 1024thr = 16 waves = qsub(4) x kq(4); q-tile 128;
// k split in half across blocks (kh) -> grid 256 (1 block/CU). K AND V staged
// once per kq-group into double-buffered LDS slabs (4 x 32KB = 128KB); each
// wave stages 4/16 segs via gld_lds. Per-CU traffic 192->64 KB/iter. The two
// kh partials combine via fp32 atomicAdd (exactly 2 commutative contributions
// per element -> bit-deterministic; output zeroed by hipMemsetAsync first).
// Numerics otherwise identical (hi/lo split, 3-MFMA products).

#define B_N 4
#define S_N 4096
#define D_N 64
#define BS_N (B_N * S_N)
#define NCHUNK 128            // 32-row chunks per batch
#define IMG_CH 8192           // bytes per chunk in every image
#define QSC (0.125f * 1.44269504088896f)

typedef __attribute__((ext_vector_type(4))) float f32x4;
typedef __attribute__((ext_vector_type(2))) float f32x2;
typedef __attribute__((ext_vector_type(8))) short short8;
typedef __attribute__((ext_vector_type(4))) unsigned u32x4;
typedef unsigned char uchar;

#define MFMA16(A, Bf, C) __builtin_amdgcn_mfma_f32_16x16x32_bf16((A), (Bf), (C), 0, 0, 0)

// Truncation hi/lo split: x == hi + lo + O(2^-16 x); residual exact in fp32.
__device__ __forceinline__ void split1(float x, unsigned short& h, unsigned short& l) {
  union { float f; unsigned u; } t; t.f = x;
  h = (unsigned short)(t.u >> 16);
  union { unsigned u; float f; } hv; hv.u = ((unsigned)h) << 16;
  union { float f; unsigned u; } r; r.f = x - hv.f;
  l = (unsigned short)(r.u >> 16);
}

__device__ __forceinline__ void splitFrag8(const f32x4 a, const f32x4 b, short8& hi, short8& lo) {
#pragma unroll
  for (int j = 0; j < 4; ++j) { unsigned short h, l; split1(a[j], h, l); hi[j] = (short)h; lo[j] = (short)l; }
#pragma unroll
  for (int j = 0; j < 4; ++j) { unsigned short h, l; split1(b[j], h, l); hi[4 + j] = (short)h; lo[4 + j] = (short)l; }
}

__device__ __forceinline__ void gld16(const void* g, void* l) {
  __builtin_amdgcn_global_load_lds((const __attribute__((address_space(1))) unsigned int*)g,
                                   (__attribute__((address_space(3))) unsigned int*)l, 16, 0, 0);
}

// ---------------------------------------------------------------------------
// prepKQ: fp32 [B*S][64] -> FRAGMENT-ORDERED chunk images (proven).
// ---------------------------------------------------------------------------
__global__ __launch_bounds__(256) void sdpa_prepKQ(const float* __restrict__ K,
                                                   const float* __restrict__ Qm,
                                                   uchar* __restrict__ Kimg,
                                                   uchar* __restrict__ Qimg) {
  const int sel = blockIdx.x >> 9;
  const int c = blockIdx.x & 127;
  const int b = (blockIdx.x >> 7) & 3;
  const float* src = sel ? Qm : K;
  uchar* img = sel ? Qimg : Kimg;
  const float scale = sel ? QSC : 1.0f;
  const int t = threadIdx.x;
  const int r = t >> 3;          // 0..31 row in chunk
  const int d0 = (t & 7) * 8;    // 0..56
  const float* s = src + ((size_t)(b * S_N + c * 32 + r)) * D_N + d0;
  f32x4 x0 = *(const f32x4*)(s);
  f32x4 x1 = *(const f32x4*)(s + 4);
  x0 *= scale; x1 *= scale;
  short8 h8, l8;
  splitFrag8(x0, x1, h8, l8);
  const int kt = r >> 4;
  const int lane = ((d0 & 31) >> 3) * 16 + (r & 15);
  const int ph = d0 >> 5;  // 0/1
  uchar* base = img + ((size_t)(b * NCHUNK + c)) * IMG_CH + kt * 4096 + lane * 16;
  *(short8*)(base + ph * 1024) = h8;
  *(short8*)(base + (2 + ph) * 1024) = l8;
}

// ---------------------------------------------------------------------------
// stats8: lPart[qs][b][k] = sum over q-slice qs (16 slices x 256 q) of exp2(s).
// grid 1024 (16 waves/CU), block 256; 64 k resident/wave; streams 8 Q chunks.
// (proven)
// ---------------------------------------------------------------------------
__global__ __launch_bounds__(256, 4) void sdpa_stats8(const uchar* __restrict__ Kimg,
                                                      const uchar* __restrict__ Qimg,
                                                      float* __restrict__ lPart) {
  const int tid = threadIdx.x, lane = tid & 63, w = tid >> 6;
  const int l15 = lane & 15, g4 = lane >> 4;
  const int xcd = blockIdx.x & 7;
  const int b = xcd >> 1;
  const int r = blockIdx.x >> 3;                  // [0,128)
  const int kt = ((r & 31) << 1) | (xcd & 1);     // [0,64) 64-k tile
  const int qs = ((r >> 5) << 2) | w;             // [0,16) 256-q slice

  short8 kh[4][2], kl[4][2];
#pragma unroll
  for (int kg = 0; kg < 4; ++kg) {
    const uchar* kc = Kimg + ((size_t)(b * NCHUNK + kt * 2 + (kg >> 1))) * IMG_CH
                    + (kg & 1) * 4096 + lane * 16;
    kh[kg][0] = *(const short8*)(kc);
    kh[kg][1] = *(const short8*)(kc + 1024);
    kl[kg][0] = *(const short8*)(kc + 2048);
    kl[kg][1] = *(const short8*)(kc + 3072);
  }

  float lacc[4][4];
#pragma unroll
  for (int kg = 0; kg < 4; ++kg)
#pragma unroll
    for (int rr = 0; rr < 4; ++rr) lacc[kg][rr] = 0.f;

  const uchar* Qbase = Qimg + ((size_t)(b * NCHUNK + qs * 8)) * IMG_CH + lane * 16;

#pragma unroll 1
  for (int it = 0; it < 8; ++it) {
    const uchar* Qc = Qbase + (size_t)it * IMG_CH;
#pragma unroll
    for (int qt = 0; qt < 2; ++qt) {
      short8 bh0 = *(const short8*)(Qc + qt * 4096);
      short8 bh1 = *(const short8*)(Qc + qt * 4096 + 1024);
      short8 bl0 = *(const short8*)(Qc + qt * 4096 + 2048);
      short8 bl1 = *(const short8*)(Qc + qt * 4096 + 3072);
#pragma unroll
      for (int kg = 0; kg < 4; ++kg) {
        f32x4 acc = {0.f, 0.f, 0.f, 0.f};
        acc = MFMA16(kl[kg][0], bh0, acc);
        acc = MFMA16(kh[kg][0], bl0, acc);
        acc = MFMA16(kh[kg][0], bh0, acc);
        acc = MFMA16(kl[kg][1], bh1, acc);
        acc = MFMA16(kh[kg][1], bl1, acc);
        acc = MFMA16(kh[kg][1], bh1, acc);
#pragma unroll
        for (int rr = 0; rr < 4; ++rr)
          lacc[kg][rr] += exp2f(acc[rr]);
      }
    }
  }

#pragma unroll
  for (int off = 1; off < 16; off <<= 1)
#pragma unroll
    for (int kg = 0; kg < 4; ++kg)
#pragma unroll
      for (int rr = 0; rr < 4; ++rr)
        lacc[kg][rr] += __shfl_xor(lacc[kg][rr], off);

  if (l15 == 0) {
#pragma unroll
    for (int kg = 0; kg < 4; ++kg)
#pragma unroll
      for (int rr = 0; rr < 4; ++rr)
        lPart[(size_t)qs * BS_N + b * S_N + kt * 64 + kg * 16 + (g4 << 2) + rr] = lacc[kg][rr];
  }
}

// ---------------------------------------------------------------------------
// prepV7: fragment-ordered permuted VT image, rcpl computed inline (proven).
// ---------------------------------------------------------------------------
__global__ __launch_bounds__(256) void sdpa_prepV7(const float* __restrict__ V,
                                                   const float* __restrict__ lPart,
                                                   uchar* __restrict__ VT) {
  __shared__ float Vs[32][65];
  __shared__ float rls[32];
  const int c = blockIdx.x & 127;
  const int b = blockIdx.x >> 7;
  const int t = threadIdx.x;
  {
    const int k = t >> 3;
    const int d0 = (t & 7) * 8;
    const float* src = V + ((size_t)(b * S_N + c * 32 + k)) * D_N + d0;
    f32x4 x0 = *(const f32x4*)(src);
    f32x4 x1 = *(const f32x4*)(src + 4);
#pragma unroll
    for (int j = 0; j < 4; ++j) { Vs[k][d0 + j] = x0[j]; Vs[k][d0 + 4 + j] = x1[j]; }
    if (t < 32) {
      float s = 0.f;
      const float* lp = lPart + b * S_N + c * 32 + t;
#pragma unroll
      for (int j = 0; j < 16; ++j) s += lp[(size_t)j * BS_N];
      rls[t] = 1.0f / s;
    }
  }
  __syncthreads();
  const int d = t >> 2;
  const int kg = t & 3;
  short8 h8, l8;
#pragma unroll
  for (int j = 0; j < 8; ++j) {
    const int cc = kg * 8 + j;
    const int k = (((cc >> 2) & 1) << 4) + (((cc >> 3)) << 2) + (cc & 3);
    float v = Vs[k][d] * rls[k];
    unsigned short h, l; split1(v, h, l);
    h8[j] = (short)h; l8[j] = (short)l;
  }
  const int lane = kg * 16 + (d & 15);
  uchar* base = VT + ((size_t)(b * NCHUNK + c)) * IMG_CH + (d >> 4) * 2048 + lane * 16;
  *(short8*)(base) = h8;
  *(short8*)(base + 1024) = l8;
}

// ---------------------------------------------------------------------------
// apply15: grid 256 = b(4, XCD-paired) x qt(32 tiles of 128 q) x kh(2 k-halves);
// block 1024 = 16 waves = qsub(4, 32 q each) x kq(4, 512 k = 16 chunks).
// Per kq-group: K+V chunk staged ONCE into dbuf LDS slab (2 x [K 8KB | V 8KB]),
// shared by 4 qsub waves; each wave stages 4/16 segs (gld_lds).
// Iter: stage(it+1, par^1) | K frags ds_read slab[par] | QK | exp/pack |
//       PV from slab[par] V | vmcnt(0) | barrier.
// Merge: 4 kq partials in-block (Comb aliases slabs), then fp32 atomicAdd
// (2 commutative contributions per element across kh blocks; out pre-zeroed).
// ---------------------------------------------------------------------------
__global__ __launch_bounds__(1024, 4) void sdpa_apply15(const float* __restrict__ Q,
                                                        const uchar* __restrict__ Kimg,
                                                        const uchar* __restrict__ VTimg,
                                                        float* __restrict__ Out) {
  __shared__ __attribute__((aligned(16))) uchar sm[131072];  // 4 kq x 2 par x 16KB

  const int tid = threadIdx.x, lane = tid & 63, w = tid >> 6;
  const int l15 = lane & 15, g4 = lane >> 4;
  const int qsub = w >> 2, kq = w & 3;
  const int xcd = blockIdx.x & 7;
  const int b = xcd >> 1;
  const int qlow = xcd & 1;
  const int rest = blockIdx.x >> 3;               // 0..31
  const int kh = rest & 1;
  const int qt = ((rest >> 1) << 1) | qlow;       // 0..31, tiles of 128 q

  // Q B-frags: this wave's 32 q rows (2 x 16), scaled + hi/lo split
  short8 qh[2][2], ql[2][2];
#pragma unroll
  for (int qg = 0; qg < 2; ++qg) {
    const int qRow = qt * 128 + qsub * 32 + qg * 16 + l15;
    const float* Qp = Q + ((size_t)(b * S_N + qRow)) * D_N;
    f32x4 x0 = *(const f32x4*)(Qp + g4 * 8);
    f32x4 x1 = *(const f32x4*)(Qp + g4 * 8 + 4);
    f32x4 y0 = *(const f32x4*)(Qp + 32 + g4 * 8);
    f32x4 y1 = *(const f32x4*)(Qp + 36 + g4 * 8);
    x0 *= QSC; x1 *= QSC; y0 *= QSC; y1 *= QSC;
    splitFrag8(x0, x1, qh[qg][0], ql[qg][0]);
    splitFrag8(y0, y1, qh[qg][1], ql[qg][1]);
  }

  f32x4 accO[2][4];
#pragma unroll
  for (int qg = 0; qg < 2; ++qg)
#pragma unroll
    for (int dt = 0; dt < 4; ++dt) accO[qg][dt] = (f32x4){0.f, 0.f, 0.f, 0.f};

  // this kq-group's chunk stream: chunks kh*64 + kq*16 + it
  const uchar* Kc = Kimg + ((size_t)(b * NCHUNK + kh * 64 + kq * 16)) * IMG_CH + lane * 16;
  const uchar* Vc = VTimg + ((size_t)(b * NCHUNK + kh * 64 + kq * 16)) * IMG_CH + lane * 16;
  uchar* const slabB = sm + kq * 32768;           // + par*16384; K at +0, V at +8192
  const int l16 = lane * 16;

  u32x4 paH[2], paL[2];

// stage this wave's 4 of 16 segs of chunk IT into parity PAR (s<8: K, else V)
#define STAGE(IT, PAR)                                                         \
  {                                                                            \
    uchar* dstB = slabB + (PAR) * 16384;                                       \
    _Pragma("unroll")                                                          \
    for (int si = 0; si < 4; ++si) {                                           \
      const int s = qsub * 4 + si;                                             \
      const uchar* src = (s < 8 ? Kc : Vc) + (size_t)(IT) * IMG_CH + (s & 7) * 1024; \
      gld16(src, dstB + s * 1024);                                             \
    }                                                                          \
  }

#define QK_FROM_LDS(SK)                                                        \
  _Pragma("unroll")                                                            \
  for (int kt = 0; kt < 2; ++kt) {                                             \
    short8 ah0 = *(const short8*)((SK) + (kt * 4 + 0) * 1024 + l16);           \
    short8 ah1 = *(const short8*)((SK) + (kt * 4 + 1) * 1024 + l16);           \
    short8 al0 = *(const short8*)((SK) + (kt * 4 + 2) * 1024 + l16);           \
    short8 al1 = *(const short8*)((SK) + (kt * 4 + 3) * 1024 + l16);           \
    _Pragma("unroll")                                                          \
    for (int qg = 0; qg < 2; ++qg) {                                           \
      f32x4 acc = {0.f, 0.f, 0.f, 0.f};                                        \
      acc = MFMA16(al0, qh[qg][0], acc);                                       \
      acc = MFMA16(ah0, ql[qg][0], acc);                                       \
      acc = MFMA16(ah0, qh[qg][0], acc);                                       \
      acc = MFMA16(al1, qh[qg][1], acc);                                       \
      acc = MFMA16(ah1, ql[qg][1], acc);                                       \
      acc = MFMA16(ah1, qh[qg][1], acc);                                       \
      _Pragma("unroll")                                                        \
      for (int pair = 0; pair < 2; ++pair) {                                   \
        float p0 = exp2f(acc[2 * pair + 0]);                                   \
        float p1 = exp2f(acc[2 * pair + 1]);                                   \
        unsigned short h0, l0, h1, l1;                                         \
        split1(p0, h0, l0);                                                    \
        split1(p1, h1, l1);                                                    \
        paH[qg][kt * 2 + pair] = (unsigned)h0 | ((unsigned)h1 << 16);          \
        paL[qg][kt * 2 + pair] = (unsigned)l0 | ((unsigned)l1 << 16);          \
      }                                                                        \
    }                                                                          \
  }

#define PV_STEP(SV)                                                            \
  {                                                                            \
    short8 pah[2], pal[2];                                                     \
    _Pragma("unroll")                                                          \
    for (int qg = 0; qg < 2; ++qg) {                                           \
      pah[qg] = __builtin_bit_cast(short8, paH[qg]);                           \
      pal[qg] = __builtin_bit_cast(short8, paL[qg]);                           \
    }                                                                          \
    _Pragma("unroll")                                                          \
    for (int dt = 0; dt < 4; ++dt) {                                           \
      short8 vh = *(const short8*)((SV) + dt * 2048 + l16);                    \
      short8 vl = *(const short8*)((SV) + dt * 2048 + 1024 + l16);             \
      _Pragma("unroll")                                                        \
      for (int qg = 0; qg < 2; ++qg) {                                         \
        accO[qg][dt] = MFMA16(pal[qg], vh, accO[qg][dt]);                      \
        accO[qg][dt] = MFMA16(pah[qg], vl, accO[qg][dt]);                      \
        accO[qg][dt] = MFMA16(pah[qg], vh, accO[qg][dt]);                      \
      }                                                                        \
    }                                                                          \
  }

  // prologue: stage chunk 0 into parity 0
  STAGE(0, 0)
  asm volatile("s_waitcnt vmcnt(0)" ::: "memory");
  __syncthreads();

#pragma unroll 1
  for (int it = 0; it < 16; ++it) {
    const int par = it & 1;
    if (it < 15) STAGE(it + 1, par ^ 1)  // flies across this iter's compute

    const uchar* sk = slabB + par * 16384;
    QK_FROM_LDS(sk)
    PV_STEP(sk + 8192)

    asm volatile("s_waitcnt vmcnt(0)" ::: "memory");  // stage(it+1) landed
    __syncthreads();                                   // visible to group
  }

#undef STAGE
#undef QK_FROM_LDS
#undef PV_STEP

  // merge 4 kq partials per qsub strip, two qg phases; then atomicAdd (kh sum)
  float* Comb = (float*)sm;
#pragma unroll
  for (int qg = 0; qg < 2; ++qg) {
    __syncthreads();
    {
      float* CombW = Comb + w * (16 * 68);
#pragma unroll
      for (int dt = 0; dt < 4; ++dt)
#pragma unroll
        for (int r = 0; r < 4; ++r)
          CombW[((g4 << 2) + r) * 68 + dt * 16 + l15] = accO[qg][dt][r];
    }
    __syncthreads();
    {
      const int qs2 = tid >> 8;          // 0..3
      const int row = (tid >> 4) & 15;   // 0..15
      const int c4 = (tid & 15) * 4;     // 0..60
      f32x4 s = {0.f, 0.f, 0.f, 0.f};
#pragma unroll
      for (int kq2 = 0; kq2 < 4; ++kq2)
        s += *(const f32x4*)(Comb + (qs2 * 4 + kq2) * (16 * 68) + row * 68 + c4);
      const int q = qt * 128 + qs2 * 32 + qg * 16 + row;
      float* op = Out + ((size_t)(b * S_N + q)) * D_N + c4;
      atomicAdd(op + 0, s[0]);
      atomicAdd(op + 1, s[1]);
      atomicAdd(op + 2, s[2]);
      atomicAdd(op + 3, s[3]);
    }
  }
}

extern "C" void kernel_launch(void* const* d_in, const int* in_sizes, int n_in,
                              void* d_out, int out_size, void* d_ws, size_t ws_size,
                              hipStream_t stream) {
  (void)in_sizes; (void)n_in;
  const float* Q = (const float*)d_in[0];
  const float* K = (const float*)d_in[1];
  const float* V = (const float*)d_in[2];
  float* out = (float*)d_out;
  uchar* ws = (uchar*)d_ws;

  const size_t imgSz = (size_t)B_N * NCHUNK * IMG_CH;          // 4 MB
  const size_t offK = 0;
  const size_t offQV = imgSz;                                  // Q image; VT aliases after stats
  const size_t offLP = 2 * imgSz;
  const size_t need = offLP + (size_t)16 * BS_N * 4;           // ~9.05 MB (proven available)

  if (ws_size < need) return;
  float* lPart = (float*)(ws + offLP);

  hipMemsetAsync(out, 0, (size_t)out_size * sizeof(float), stream);
  sdpa_prepKQ<<<dim3(1024), dim3(256), 0, stream>>>(K, Q, ws + offK, ws + offQV);
  sdpa_stats8<<<dim3(1024), dim3(256), 0, stream>>>(ws + offK, ws + offQV, lPart);
  sdpa_prepV7<<<dim3(512), dim3(256), 0, stream>>>(V, lPart, ws + offQV);
  sdpa_apply15<<<dim3(256), dim3(1024), 0, stream>>>(Q, ws + offK, ws + offQV, out);
}

// Round 15
// 97.427 us; speedup vs baseline: 1.2389x; 1.2389x over previous
//
#include <hip/hip_runtime.h>

// B=4, S=4096, D=64, fp32. Softmax over QUERY axis (per key-column norm):
//   out[b,q,:] = sum_k exp(s[q,k]) * (1/sum_q' exp(s[q',k])) * V[k,:],  s = Q.K^T/8
// v16 = v14 (proven best: apply 62.5us) + balanced staging: the V slab stage is
// split across the wave pair (qsub0 -> segs 0-3, qsub1 -> segs 4-7) instead of
// qsub0 staging all 8 -> balanced vmem issue + equal vmcnt(0) drain work ->
// less barrier skew. v15's 4-way/atomics direction REVERTED (regressed to 80us:
// lost PV-covers-K rotation + 48MB atomic/memset traffic; falsified bytes-bound
// model). Numerics identical (hi/lo split, 3-MFMA products).

#define B_N 4
#define S_N 4096
#define D_N 64
#define BS_N (B_N * S_N)
#define NCHUNK 128            // 32-row chunks per batch
#define IMG_CH 8192           // bytes per chunk in every image
#define QSC (0.125f * 1.44269504088896f)

typedef __attribute__((ext_vector_type(4))) float f32x4;
typedef __attribute__((ext_vector_type(2))) float f32x2;
typedef __attribute__((ext_vector_type(8))) short short8;
typedef __attribute__((ext_vector_type(4))) unsigned u32x4;
typedef unsigned char uchar;

#define MFMA16(A, Bf, C) __builtin_amdgcn_mfma_f32_16x16x32_bf16((A), (Bf), (C), 0, 0, 0)

// Truncation hi/lo split: x == hi + lo + O(2^-16 x); residual exact in fp32.
__device__ __forceinline__ void split1(float x, unsigned short& h, unsigned short& l) {
  union { float f; unsigned u; } t; t.f = x;
  h = (unsigned short)(t.u >> 16);
  union { unsigned u; float f; } hv; hv.u = ((unsigned)h) << 16;
  union { float f; unsigned u; } r; r.f = x - hv.f;
  l = (unsigned short)(r.u >> 16);
}

__device__ __forceinline__ void splitFrag8(const f32x4 a, const f32x4 b, short8& hi, short8& lo) {
#pragma unroll
  for (int j = 0; j < 4; ++j) { unsigned short h, l; split1(a[j], h, l); hi[j] = (short)h; lo[j] = (short)l; }
#pragma unroll
  for (int j = 0; j < 4; ++j) { unsigned short h, l; split1(b[j], h, l); hi[4 + j] = (short)h; lo[4 + j] = (short)l; }
}

__device__ __forceinline__ void gld16(const void* g, void* l) {
  __builtin_amdgcn_global_load_lds((const __attribute__((address_space(1))) unsigned int*)g,
                                   (__attribute__((address_space(3))) unsigned int*)l, 16, 0, 0);
}

// ---------------------------------------------------------------------------
// prepKQ: fp32 [B*S][64] -> FRAGMENT-ORDERED chunk images (proven).
// ---------------------------------------------------------------------------
__global__ __launch_bounds__(256) void sdpa_prepKQ(const float* __restrict__ K,
                                                   const float* __restrict__ Qm,
                                                   uchar* __restrict__ Kimg,
                                                   uchar* __restrict__ Qimg) {
  const int sel = blockIdx.x >> 9;
  const int c = blockIdx.x & 127;
  const int b = (blockIdx.x >> 7) & 3;
  const float* src = sel ? Qm : K;
  uchar* img = sel ? Qimg : Kimg;
  const float scale = sel ? QSC : 1.0f;
  const int t = threadIdx.x;
  const int r = t >> 3;          // 0..31 row in chunk
  const int d0 = (t & 7) * 8;    // 0..56
  const float* s = src + ((size_t)(b * S_N + c * 32 + r)) * D_N + d0;
  f32x4 x0 = *(const f32x4*)(s);
  f32x4 x1 = *(const f32x4*)(s + 4);
  x0 *= scale; x1 *= scale;
  short8 h8, l8;
  splitFrag8(x0, x1, h8, l8);
  const int kt = r >> 4;
  const int lane = ((d0 & 31) >> 3) * 16 + (r & 15);
  const int ph = d0 >> 5;  // 0/1
  uchar* base = img + ((size_t)(b * NCHUNK + c)) * IMG_CH + kt * 4096 + lane * 16;
  *(short8*)(base + ph * 1024) = h8;
  *(short8*)(base + (2 + ph) * 1024) = l8;
}

// ---------------------------------------------------------------------------
// stats8: lPart[qs][b][k] = sum over q-slice qs (16 slices x 256 q) of exp2(s).
// grid 1024 (16 waves/CU), block 256; 64 k resident/wave; streams 8 Q chunks.
// (proven; ~62% of MFMA ceiling, barrier-free)
// ---------------------------------------------------------------------------
__global__ __launch_bounds__(256, 4) void sdpa_stats8(const uchar* __restrict__ Kimg,
                                                      const uchar* __restrict__ Qimg,
                                                      float* __restrict__ lPart) {
  const int tid = threadIdx.x, lane = tid & 63, w = tid >> 6;
  const int l15 = lane & 15, g4 = lane >> 4;
  const int xcd = blockIdx.x & 7;
  const int b = xcd >> 1;
  const int r = blockIdx.x >> 3;                  // [0,128)
  const int kt = ((r & 31) << 1) | (xcd & 1);     // [0,64) 64-k tile
  const int qs = ((r >> 5) << 2) | w;             // [0,16) 256-q slice

  short8 kh[4][2], kl[4][2];
#pragma unroll
  for (int kg = 0; kg < 4; ++kg) {
    const uchar* kc = Kimg + ((size_t)(b * NCHUNK + kt * 2 + (kg >> 1))) * IMG_CH
                    + (kg & 1) * 4096 + lane * 16;
    kh[kg][0] = *(const short8*)(kc);
    kh[kg][1] = *(const short8*)(kc + 1024);
    kl[kg][0] = *(const short8*)(kc + 2048);
    kl[kg][1] = *(const short8*)(kc + 3072);
  }

  float lacc[4][4];
#pragma unroll
  for (int kg = 0; kg < 4; ++kg)
#pragma unroll
    for (int rr = 0; rr < 4; ++rr) lacc[kg][rr] = 0.f;

  const uchar* Qbase = Qimg + ((size_t)(b * NCHUNK + qs * 8)) * IMG_CH + lane * 16;

#pragma unroll 1
  for (int it = 0; it < 8; ++it) {
    const uchar* Qc = Qbase + (size_t)it * IMG_CH;
#pragma unroll
    for (int qt = 0; qt < 2; ++qt) {
      short8 bh0 = *(const short8*)(Qc + qt * 4096);
      short8 bh1 = *(const short8*)(Qc + qt * 4096 + 1024);
      short8 bl0 = *(const short8*)(Qc + qt * 4096 + 2048);
      short8 bl1 = *(const short8*)(Qc + qt * 4096 + 3072);
#pragma unroll
      for (int kg = 0; kg < 4; ++kg) {
        f32x4 acc = {0.f, 0.f, 0.f, 0.f};
        acc = MFMA16(kl[kg][0], bh0, acc);
        acc = MFMA16(kh[kg][0], bl0, acc);
        acc = MFMA16(kh[kg][0], bh0, acc);
        acc = MFMA16(kl[kg][1], bh1, acc);
        acc = MFMA16(kh[kg][1], bl1, acc);
        acc = MFMA16(kh[kg][1], bh1, acc);
#pragma unroll
        for (int rr = 0; rr < 4; ++rr)
          lacc[kg][rr] += exp2f(acc[rr]);
      }
    }
  }

#pragma unroll
  for (int off = 1; off < 16; off <<= 1)
#pragma unroll
    for (int kg = 0; kg < 4; ++kg)
#pragma unroll
      for (int rr = 0; rr < 4; ++rr)
        lacc[kg][rr] += __shfl_xor(lacc[kg][rr], off);

  if (l15 == 0) {
#pragma unroll
    for (int kg = 0; kg < 4; ++kg)
#pragma unroll
      for (int rr = 0; rr < 4; ++rr)
        lPart[(size_t)qs * BS_N + b * S_N + kt * 64 + kg * 16 + (g4 << 2) + rr] = lacc[kg][rr];
  }
}

// ---------------------------------------------------------------------------
// prepV7: fragment-ordered permuted VT image, rcpl computed inline (proven).
// ---------------------------------------------------------------------------
__global__ __launch_bounds__(256) void sdpa_prepV7(const float* __restrict__ V,
                                                   const float* __restrict__ lPart,
                                                   uchar* __restrict__ VT) {
  __shared__ float Vs[32][65];
  __shared__ float rls[32];
  const int c = blockIdx.x & 127;
  const int b = blockIdx.x >> 7;
  const int t = threadIdx.x;
  {
    const int k = t >> 3;
    const int d0 = (t & 7) * 8;
    const float* src = V + ((size_t)(b * S_N + c * 32 + k)) * D_N + d0;
    f32x4 x0 = *(const f32x4*)(src);
    f32x4 x1 = *(const f32x4*)(src + 4);
#pragma unroll
    for (int j = 0; j < 4; ++j) { Vs[k][d0 + j] = x0[j]; Vs[k][d0 + 4 + j] = x1[j]; }
    if (t < 32) {
      float s = 0.f;
      const float* lp = lPart + b * S_N + c * 32 + t;
#pragma unroll
      for (int j = 0; j < 16; ++j) s += lp[(size_t)j * BS_N];
      rls[t] = 1.0f / s;
    }
  }
  __syncthreads();
  const int d = t >> 2;
  const int kg = t & 3;
  short8 h8, l8;
#pragma unroll
  for (int j = 0; j < 8; ++j) {
    const int cc = kg * 8 + j;
    const int k = (((cc >> 2) & 1) << 4) + (((cc >> 3)) << 2) + (cc & 3);
    float v = Vs[k][d] * rls[k];
    unsigned short h, l; split1(v, h, l);
    h8[j] = (short)h; l8[j] = (short)l;
  }
  const int lane = kg * 16 + (d & 15);
  uchar* base = VT + ((size_t)(b * NCHUNK + c)) * IMG_CH + (d >> 4) * 2048 + lane * 16;
  *(short8*)(base) = h8;
  *(short8*)(base + 1024) = l8;
}

// ---------------------------------------------------------------------------
// apply16: grid 256 = b(4, XCD-paired) x qt(64 tiles of 64 q); block 1024 =
// 16 waves = qsub(2, 32 q each) x kq(8 k-eighths, 16 chunks each).
// Wave pair (qsub0/1, kq) shares one chunk stream: V staged into shared dbuf
// slab SPLIT ACROSS THE PAIR (qsub0: segs 0-3, qsub1: segs 4-7); K reg-loads
// duplicated (barrier-locked -> L1 twin).
// Per iter (v13 rotation): K(it) | SB | PV(it-1) slab[(it-1)&1] | SB |
// stage half of V(it)->slab[it&1] | QK(it) | vmcnt(0) | __syncthreads.
// LDS: 8 kq x 2 x 8KB = 128KB; merge Comb aliases after final barrier.
// ---------------------------------------------------------------------------
__global__ __launch_bounds__(1024, 4) void sdpa_apply16(const float* __restrict__ Q,
                                                        const uchar* __restrict__ Kimg,
                                                        const uchar* __restrict__ VTimg,
                                                        float* __restrict__ Out) {
  __shared__ __attribute__((aligned(16))) uchar sm[131072];  // V slabs; Comb aliases

  const int tid = threadIdx.x, lane = tid & 63, w = tid >> 6;
  const int l15 = lane & 15, g4 = lane >> 4;
  const int qsub = w >> 3, kq = w & 7;
  const int xcd = blockIdx.x & 7;
  const int b = xcd >> 1;
  const int qt = ((blockIdx.x >> 3) << 1) | (xcd & 1);  // [0,64), tiles of 64 q

  // Q B-frags: this wave's 32 q rows (2 x 16), scaled + hi/lo split
  short8 qh[2][2], ql[2][2];
#pragma unroll
  for (int qg = 0; qg < 2; ++qg) {
    const int qRow = qt * 64 + qsub * 32 + qg * 16 + l15;
    const float* Qp = Q + ((size_t)(b * S_N + qRow)) * D_N;
    f32x4 x0 = *(const f32x4*)(Qp + g4 * 8);
    f32x4 x1 = *(const f32x4*)(Qp + g4 * 8 + 4);
    f32x4 y0 = *(const f32x4*)(Qp + 32 + g4 * 8);
    f32x4 y1 = *(const f32x4*)(Qp + 36 + g4 * 8);
    x0 *= QSC; x1 *= QSC; y0 *= QSC; y1 *= QSC;
    splitFrag8(x0, x1, qh[qg][0], ql[qg][0]);
    splitFrag8(y0, y1, qh[qg][1], ql[qg][1]);
  }

  f32x4 accO[2][4];
#pragma unroll
  for (int qg = 0; qg < 2; ++qg)
#pragma unroll
    for (int dt = 0; dt < 4; ++dt) accO[qg][dt] = (f32x4){0.f, 0.f, 0.f, 0.f};

  const uchar* Kc = Kimg + ((size_t)(b * NCHUNK + kq * 16)) * IMG_CH + lane * 16;
  const uchar* Vc = VTimg + ((size_t)(b * NCHUNK + kq * 16)) * IMG_CH + lane * 16;
  uchar* const slab0 = sm + kq * 16384;   // [parity][8192]
  const int l16 = lane * 16;

  u32x4 paH[2], paL[2];                   // P regs: VALU-produced, loop-carried

#define QK_FROM(KB)                                                            \
  _Pragma("unroll")                                                            \
  for (int kt = 0; kt < 2; ++kt) {                                             \
    short8 ah0 = KB[kt][0], ah1 = KB[kt][1];                                   \
    short8 al0 = KB[kt][2], al1 = KB[kt][3];                                   \
    _Pragma("unroll")                                                          \
    for (int qg = 0; qg < 2; ++qg) {                                           \
      f32x4 acc = {0.f, 0.f, 0.f, 0.f};                                        \
      acc = MFMA16(al0, qh[qg][0], acc);                                       \
      acc = MFMA16(ah0, ql[qg][0], acc);                                       \
      acc = MFMA16(ah0, qh[qg][0], acc);                                       \
      acc = MFMA16(al1, qh[qg][1], acc);                                       \
      acc = MFMA16(ah1, ql[qg][1], acc);                                       \
      acc = MFMA16(ah1, qh[qg][1], acc);                                       \
      _Pragma("unroll")                                                        \
      for (int pair = 0; pair < 2; ++pair) {                                   \
        float p0 = exp2f(acc[2 * pair + 0]);                                   \
        float p1 = exp2f(acc[2 * pair + 1]);                                   \
        unsigned short h0, l0, h1, l1;                                         \
        split1(p0, h0, l0);                                                    \
        split1(p1, h1, l1);                                                    \
        paH[qg][kt * 2 + pair] = (unsigned)h0 | ((unsigned)h1 << 16);          \
        paL[qg][kt * 2 + pair] = (unsigned)l0 | ((unsigned)l1 << 16);          \
      }                                                                        \
    }                                                                          \
  }

#define PV_STEP(SLAB)                                                          \
  {                                                                            \
    short8 pah[2], pal[2];                                                     \
    _Pragma("unroll")                                                          \
    for (int qg = 0; qg < 2; ++qg) {                                           \
      pah[qg] = __builtin_bit_cast(short8, paH[qg]);                           \
      pal[qg] = __builtin_bit_cast(short8, paL[qg]);                           \
    }                                                                          \
    _Pragma("unroll")                                                          \
    for (int dt = 0; dt < 4; ++dt) {                                           \
      short8 vh = *(const short8*)((SLAB) + dt * 2048 + l16);                  \
      short8 vl = *(const short8*)((SLAB) + dt * 2048 + 1024 + l16);           \
      _Pragma("unroll")                                                        \
      for (int qg = 0; qg < 2; ++qg) {                                         \
        accO[qg][dt] = MFMA16(pal[qg], vh, accO[qg][dt]);                      \
        accO[qg][dt] = MFMA16(pah[qg], vl, accO[qg][dt]);                      \
        accO[qg][dt] = MFMA16(pah[qg], vh, accO[qg][dt]);                      \
      }                                                                        \
    }                                                                          \
  }

// stage this wave's HALF of V chunk IT into parity PAR (qsub0: 0-3, qsub1: 4-7)
#define STAGE_HALF(IT, PAR)                                                    \
  {                                                                            \
    const uchar* Vn = Vc + (size_t)(IT) * IMG_CH;                              \
    uchar* slabW = slab0 + (PAR) * 8192;                                       \
    _Pragma("unroll")                                                          \
    for (int si = 0; si < 4; ++si) {                                           \
      const int s = qsub * 4 + si;                                             \
      gld16(Vn + s * 1024, slabW + s * 1024);                                  \
    }                                                                          \
  }

  // prologue: K(0), V(0)->slab[0] (split), QK(0), pin, barrier
  {
    short8 kb[2][4];
#pragma unroll
    for (int kt = 0; kt < 2; ++kt)
#pragma unroll
      for (int p = 0; p < 4; ++p)
        kb[kt][p] = *(const short8*)(Kc + (kt * 4 + p) * 1024);
    STAGE_HALF(0, 0)
    QK_FROM(kb)
    asm volatile("s_waitcnt vmcnt(0)" ::: "memory");
    __syncthreads();
  }

#pragma unroll 1
  for (int it = 1; it < 16; ++it) {
    // K(it): transient regs, issued FIRST (covered by PV below)
    short8 kb[2][4];
    {
      const uchar* Kn = Kc + (size_t)it * IMG_CH;
#pragma unroll
      for (int kt = 0; kt < 2; ++kt)
#pragma unroll
        for (int p = 0; p < 4; ++p)
          kb[kt][p] = *(const short8*)(Kn + (kt * 4 + p) * 1024);
    }
    __builtin_amdgcn_sched_barrier(0);  // K loads issue before PV

    PV_STEP(slab0 + ((it - 1) & 1) * 8192)  // PV(it-1) covers K(it) latency

    __builtin_amdgcn_sched_barrier(0);  // slab reads before staging

    STAGE_HALF(it, it & 1)  // half of V(it), covered by QK+exp

    QK_FROM(kb)  // K landed during PV

    asm volatile("s_waitcnt vmcnt(0)" ::: "memory");  // V(it) staged
    __syncthreads();  // V(it) visible to both qsub waves; streams stay locked
  }

  PV_STEP(slab0 + 8192)  // epilogue: PV(15), parity 1

#undef QK_FROM
#undef PV_STEP
#undef STAGE_HALF

  // merge 8 kq partials per qsub, two 16-q phases (Comb aliases the V slabs)
  float* Comb = (float*)sm;
#pragma unroll
  for (int qg = 0; qg < 2; ++qg) {
    __syncthreads();   // all waves' slab reads done / previous phase consumed
    {
      float* CombW = Comb + w * (16 * 68);
#pragma unroll
      for (int dt = 0; dt < 4; ++dt)
#pragma unroll
        for (int r = 0; r < 4; ++r)
          CombW[((g4 << 2) + r) * 68 + dt * 16 + l15] = accO[qg][dt][r];
    }
    __syncthreads();
    {
      const int qs2 = tid >> 9;            // 0..1
      const int row = (tid >> 5) & 15;     // 0..15
      const int c2 = (tid & 31) * 2;       // 0..62
      f32x2 s = {0.f, 0.f};
#pragma unroll
      for (int kq2 = 0; kq2 < 8; ++kq2)
        s += *(const f32x2*)(Comb + (qs2 * 8 + kq2) * (16 * 68) + row * 68 + c2);
      *(f32x2*)(Out + ((size_t)(b * S_N + qt * 64 + qs2 * 32 + qg * 16 + row)) * D_N + c2) = s;
    }
  }
}

extern "C" void kernel_launch(void* const* d_in, const int* in_sizes, int n_in,
                              void* d_out, int out_size, void* d_ws, size_t ws_size,
                              hipStream_t stream) {
  (void)in_sizes; (void)n_in; (void)out_size;
  const float* Q = (const float*)d_in[0];
  const float* K = (const float*)d_in[1];
  const float* V = (const float*)d_in[2];
  float* out = (float*)d_out;
  uchar* ws = (uchar*)d_ws;

  const size_t imgSz = (size_t)B_N * NCHUNK * IMG_CH;          // 4 MB
  const size_t offK = 0;
  const size_t offQV = imgSz;                                  // Q image; VT aliases after stats
  const size_t offLP = 2 * imgSz;
  const size_t need = offLP + (size_t)16 * BS_N * 4;           // ~9.05 MB (proven available)

  if (ws_size < need) return;
  float* lPart = (float*)(ws + offLP);

  sdpa_prepKQ<<<dim3(1024), dim3(256), 0, stream>>>(K, Q, ws + offK, ws + offQV);
  sdpa_stats8<<<dim3(1024), dim3(256), 0, stream>>>(ws + offK, ws + offQV, lPart);
  sdpa_prepV7<<<dim3(512), dim3(256), 0, stream>>>(V, lPart, ws + offQV);
  sdpa_apply16<<<dim3(256), dim3(1024), 0, stream>>>(Q, ws + offK, ws + offQV, out);
}